// Round 4
// baseline (391.888 us; speedup 1.0000x reference)
//
#include <hip/hip_runtime.h>
#include <stdint.h>
#include <stddef.h>

// Problem constants
#define T_ 512
#define B_ 256
#define IN_ 292
#define H_ 128
#define G4_ 512     // 4*H
#define TB_ 131072  // T_*B_
#define LCH 32      // time-chunk length for the segment scan
#define NCH 16      // number of chunks (T_/LCH)
#define KP_ 320     // K padded to 10*32

typedef short bf16x8 __attribute__((ext_vector_type(8)));
typedef float f32x4 __attribute__((ext_vector_type(4)));

__device__ __forceinline__ unsigned short f2bf(float f) {
  unsigned u = __float_as_uint(f);
  u += 0x7FFFu + ((u >> 16) & 1u);   // RTNE
  return (unsigned short)(u >> 16);
}
__device__ __forceinline__ float bf2f(unsigned short s) {
  return __uint_as_float(((unsigned)s) << 16);
}
// two fp32 -> packed bf16 pair (round-half-up). 1.5 VALU ops/elem.
__device__ __forceinline__ unsigned bfpack2(float a, float b) {
  unsigned ua = __float_as_uint(a) + 0x8000u;
  unsigned ub = __float_as_uint(b) + 0x8000u;
  return __builtin_amdgcn_perm(ub, ua, 0x07060302u);  // [ub.hi16 : ua.hi16]
}
__device__ __forceinline__ float sigf(float x) {
  return __builtin_amdgcn_rcpf(1.0f + __expf(-x));
}
__device__ __forceinline__ float tanhf_(float x) {
  return 1.0f - 2.0f * __builtin_amdgcn_rcpf(__expf(2.0f * x) + 1.0f);
}
// LDS-only barrier: lgkmcnt(0)+s_barrier, leaves global loads/stores in flight.
__device__ __forceinline__ void barrier_lds() {
  asm volatile("s_waitcnt lgkmcnt(0)\n\ts_barrier" ::: "memory");
}
// Counted-vmcnt barriers (T3/T4): allow the newest N VMEM ops (this iter's
// W-prefetch + x-stage) to stay in flight across the barrier; everything
// older (incl. the tile about to be read) is proven complete.
#define BAR_VM(N)                                                         \
  do {                                                                    \
    asm volatile("s_waitcnt vmcnt(" #N ") lgkmcnt(0)\n\ts_barrier" :::    \
                 "memory");                                               \
    __builtin_amdgcn_sched_barrier(0);                                    \
  } while (0)
// async 16B global->LDS (direct-to-LDS DMA, no VGPR round trip)
__device__ __forceinline__ void gload_lds16(const float* g, float* l) {
  __builtin_amdgcn_global_load_lds(
      (const __attribute__((address_space(1))) void*)g,
      (__attribute__((address_space(3))) void*)l, 16, 0, 0);
}
// load one lane's 4 cell-quads (32 B contiguous): pr[r] = {i,f,g,o} of cell r.
__device__ __forceinline__ void load_pr(const unsigned short* p, ushort4* pr) {
  union { uint4 v; ushort4 s[2]; } a, b;
  a.v = *(const uint4*)p;
  b.v = *(const uint4*)(p + 8);
  pr[0] = a.s[0]; pr[1] = a.s[1]; pr[2] = b.s[0]; pr[3] = b.s[1];
}

// ---------------------------------------------------------------------------
// K0w v3: W_ih fp32 [512][292] -> Wf, FRAG-MAJOR bf16 layout:
//   Wf[((g16*10 + it)*64 + lane)*8 .. +8] = row jj = 16*g16 + (lane&15),
//   k = it*32 + (lane>>4)*8 .. +8, with jj -> W_ih row (jj&3)*128 + (jj>>2)
//   (jj = cell*4 + gate). Each k1 af-load is 64 lanes x 16B fully contiguous.
//   Zero-pads k 292..319. Also emits reordered bias2[jj] fp32.
// ---------------------------------------------------------------------------
__global__ __launch_bounds__(256) void k0w_cvt(
    const float* __restrict__ Wih, const float* __restrict__ bih,
    const float* __restrict__ bhh, unsigned short* __restrict__ Wf,
    float* __restrict__ bias2) {
  const int g = blockIdx.x * 256 + threadIdx.x;  // 0..20479
  const int lane = g & 63;
  const int rest = g >> 6;          // 0..319
  const int it = rest % 10;
  const int g16 = rest / 10;        // 0..31
  const int jj = g16 * 16 + (lane & 15);
  const int src = (jj & 3) * 128 + (jj >> 2);
  const int c0 = it * 32 + (lane >> 4) * 8;
  if (g < 512) {
    const int sb = (g & 3) * 128 + (g >> 2);
    bias2[g] = bih[sb] + bhh[sb];
  }
  float4 a = {0.f, 0.f, 0.f, 0.f}, b = {0.f, 0.f, 0.f, 0.f};
  const float* p = Wih + (size_t)src * IN_ + c0;
  if (c0 + 8 <= IN_) { a = *(const float4*)p; b = *(const float4*)(p + 4); }
  else if (c0 < IN_) { a = *(const float4*)p; }  // c0==288: cols 288..291
  uint4 o;
  o.x = bfpack2(a.x, a.y); o.y = bfpack2(a.z, a.w);
  o.z = bfpack2(b.x, b.y); o.w = bfpack2(b.z, b.w);
  *(uint4*)&Wf[(size_t)g * 8] = o;  // g == (g16*10+it)*64 + lane
}

// ---------------------------------------------------------------------------
// K1 v6: pre2[m][jj] (bf16) = x @ W^T + bias2.
// Round-3 post-mortem: __syncthreads() = vmcnt(0) drain of the 1-deep x
// stage every iteration (~4800 idle cy/iter at 2 waves/SIMD, no 2nd block).
// Fix = counted-vmcnt barriers + 2-tiles-deep staging:
//  - 3 LDS x-buffers; stage tile t+2 during iter t (into the buffer freed
//    at the end of iter t-1).
//  - per-iter barrier: s_waitcnt vmcnt(N) lgkmcnt(0); s_barrier with
//    N = ops issued THIS iter (4 afn + 2 stage = 6; 4 at git38; 0 at git39).
//    In-order vmcnt queue => tile t+1's stage (issued >=1 iter ago) is
//    complete, tile t+2's loads stay in flight ACROSS the barrier.
//  - issue order pinned afn -> stage -> frags via sched_barrier(0), so the
//    compiler's auto-wait for afn (vmcnt(8)) never drains the stage queue.
//  - epilogue barriers stay lgkm-only; pre2 stores drain lazily at the
//    next counted barrier (oldest in queue by then).
// ---------------------------------------------------------------------------
__device__ __forceinline__ void k1_stage(
    const float* __restrict__ x, float* ldsbuf, int bid4, int g2,
    int w, int lane) {
  const int jx = g2 / 10, kt = g2 % 10;
#pragma unroll
  for (int j = 0; j < 2; ++j) {
    const int r = w * 16 + j * 8 + (lane >> 3);       // tile row 0..127
    const int tq = (lane & 7) ^ (r & 7);              // true 16B-quad index
    const float* src =
        x + (size_t)((bid4 + jx) * 128 + r) * IN_ + kt * 32 + tq * 4;
    float* dst = ldsbuf + w * 512 + j * 256;          // wave-uniform base
    if (kt < 9 || tq == 0) gload_lds16(src, dst);
  }
}

__global__ __launch_bounds__(512, 2) void k1_pregemm(
    const float* __restrict__ x, const unsigned short* __restrict__ Wf,
    const float* __restrict__ bias2, unsigned short* __restrict__ pre2) {
  __shared__ float xtf[3][128 * 32];          // 3 x 16 KB fp32 x tiles
  __shared__ unsigned short ep[64 * 520];     // 65 KB epilogue staging

  const int tid = threadIdx.x;
  const int w = tid >> 6;        // 0..7: jj group [64w, 64w+64)
  const int lane = tid & 63;
  const int l15 = lane & 15;
  const int q = lane >> 4;
  const int bid4 = blockIdx.x * 4;

  // W frag base for this wave: af(s,it) at wfbase + (s*10+it)*512 ushorts
  const unsigned short* wfbase = Wf + ((size_t)(4 * w) * 10 * 64 + lane) * 8;

  f32x4 acc[4][8];
#pragma unroll
  for (int s = 0; s < 4; s++)
#pragma unroll
    for (int ms = 0; ms < 8; ms++) acc[s][ms] = (f32x4){0.f, 0.f, 0.f, 0.f};

  // prologue: stage tiles 0 and 1, load W frags for tile 0.
  // queue: [s0 x2, s1 x2, af x4] -> vmcnt(6) proves s0 complete.
  k1_stage(x, &xtf[0][0], bid4, 0, w, lane);
  k1_stage(x, &xtf[1][0], bid4, 1, w, lane);
  bf16x8 af[4];
#pragma unroll
  for (int s = 0; s < 4; s++)
    af[s] = *(const bf16x8*)(wfbase + (s * 10 + 0) * 512);
  BAR_VM(6);

  int bc = 0;  // buffer holding tile git
#pragma unroll 1
  for (int git = 0; git < 40; ++git) {
    const int kt = git % 10;
    // 1) W prefetch for next iter (FIRST in queue, so its auto-wait
    //    leaves the newer stage ops in flight)
    bf16x8 afn[4];
    if (git < 39) {
      const int nit = (kt == 9) ? 0 : kt + 1;
#pragma unroll
      for (int s = 0; s < 4; s++)
        afn[s] = *(const bf16x8*)(wfbase + (s * 10 + nit) * 512);
    }
    __builtin_amdgcn_sched_barrier(0);
    // 2) stage tile git+2 into buffer (bc+2)%3 (freed at end of iter git-1)
    if (git + 2 < 40) {
      const int bs = (bc == 0) ? 2 : bc - 1;
      k1_stage(x, &xtf[bs][0], bid4, git + 2, w, lane);
    }
    __builtin_amdgcn_sched_barrier(0);
    // 3) fragments from fp32 LDS (swizzled read) + convert to bf16
    const float* xb = &xtf[bc][0];
    bf16x8 bfr[8];
#pragma unroll
    for (int ms = 0; ms < 8; ms++) {
      const int r = 16 * ms + l15;
      const int a0 = (2 * q) ^ (r & 7), a1 = (2 * q + 1) ^ (r & 7);
      const float4 u0 = *(const float4*)&xb[r * 32 + a0 * 4];
      const float4 u1 = *(const float4*)&xb[r * 32 + a1 * 4];
      union { unsigned u[4]; bf16x8 v; } cv;
      cv.u[0] = bfpack2(u0.x, u0.y); cv.u[1] = bfpack2(u0.z, u0.w);
      cv.u[2] = bfpack2(u1.x, u1.y); cv.u[3] = bfpack2(u1.z, u1.w);
      bfr[ms] = cv.v;
    }
    // 4) 32 MFMA
#pragma unroll
    for (int s = 0; s < 4; s++)
#pragma unroll
      for (int ms = 0; ms < 8; ms++)
        acc[s][ms] = __builtin_amdgcn_mfma_f32_16x16x32_bf16(
            af[s], bfr[ms], acc[s][ms], 0, 0, 0);
#pragma unroll
    for (int s = 0; s < 4; s++) af[s] = afn[s];
    // 5) counted barrier: keep THIS iter's (afn + stage) ops in flight
    if (git <= 37) BAR_VM(6);
    else if (git == 38) BAR_VM(4);
    else BAR_VM(0);

    if (kt == 9) {
      // -------- epilogue for m-tile j = git/10: rows m0..m0+127 ----------
      const int m0 = (bid4 + git / 10) * 128;
      float4 bb[4];
#pragma unroll
      for (int s = 0; s < 4; s++)
        bb[s] = *(const float4*)&bias2[64 * w + 16 * s + 4 * q];
#pragma unroll
      for (int st = 0; st < 2; ++st) {
        // every wave writes its jj-cols for rows [64st, 64st+64)
#pragma unroll
        for (int mm = 0; mm < 4; ++mm) {
          const int ms = 4 * st + mm;
#pragma unroll
          for (int s = 0; s < 4; ++s) {
            uint2 v;
            v.x = bfpack2(acc[s][ms][0] + bb[s].x, acc[s][ms][1] + bb[s].y);
            v.y = bfpack2(acc[s][ms][2] + bb[s].z, acc[s][ms][3] + bb[s].w);
            *(uint2*)&ep[(16 * mm + l15) * 520 + 64 * w + 16 * s + 4 * q] = v;
          }
        }
        barrier_lds();
        // full-row stores: wave w, pass p -> row 8p+w (1 KB contiguous)
#pragma unroll
        for (int p = 0; p < 8; ++p) {
          const int r = 8 * p + w;
          uint4 v = *(const uint4*)&ep[r * 520 + lane * 8];
          *(uint4*)&pre2[((size_t)(m0 + 64 * st + r) << 9) + lane * 8] = v;
        }
        barrier_lds();
      }
      if (git < 39) {  // re-arm accumulators for the next m-tile
#pragma unroll
        for (int s = 0; s < 4; s++)
#pragma unroll
          for (int ms = 0; ms < 8; ms++) acc[s][ms] = (f32x4){0.f, 0.f, 0.f, 0.f};
      }
    }
    bc = (bc == 2) ? 0 : bc + 1;
  }
}

// ---------------------------------------------------------------------------
// Segment-scan LSTM (exact for any done; fast because P(reset)=0.5).
// pre2 layout: element m*512 + cell*4 + gate -> one 32B load per lane gives
// pr[r] = {i,f,g,o} of cell kcell+r.
// ---------------------------------------------------------------------------
__global__ __launch_bounds__(512) void k2a_chunk(
    const unsigned short* __restrict__ pre2, const float* __restrict__ Whh,
    const int* __restrict__ done, unsigned short* __restrict__ hidden,
    unsigned short* __restrict__ hfin, float* __restrict__ cfin) {
  __shared__ unsigned short hs[2][16 * 136];
  __shared__ int dns[LCH * 16];

  const int bg = blockIdx.x & 15;
  const int ck = blockIdx.x >> 4;
  const int t0 = ck * LCH;
  const int tid = threadIdx.x;
  const int w = tid >> 6;
  const int lane = tid & 63;
  const int l15 = lane & 15;
  const int q = lane >> 4;
  const int bglob = bg * 16 + l15;
  const int kcell = 16 * w + 4 * q;
  const int kq16 = kcell * 4;  // element offset of this lane's 4 cell-quads

  {
    const int r = tid >> 4, c = tid & 15;
    dns[tid] = done[(size_t)(t0 + r) * B_ + bg * 16 + c];
  }

  bf16x8 wf[4][4];
#pragma unroll
  for (int tI = 0; tI < 4; tI++) {
    const int jg = 16 * (w + 8 * tI) + l15;
#pragma unroll
    for (int kc = 0; kc < 4; kc++) {
      const float* p = Whh + (size_t)jg * H_ + kc * 32 + q * 8;
      float4 u0 = *(const float4*)p;
      float4 u1 = *(const float4*)(p + 4);
      bf16x8 r;
      r[0]=(short)f2bf(u0.x); r[1]=(short)f2bf(u0.y); r[2]=(short)f2bf(u0.z); r[3]=(short)f2bf(u0.w);
      r[4]=(short)f2bf(u1.x); r[5]=(short)f2bf(u1.y); r[6]=(short)f2bf(u1.z); r[7]=(short)f2bf(u1.w);
      wf[tI][kc] = r;
    }
  }

  float c_[4] = {0.f, 0.f, 0.f, 0.f};
  {
    const int b = tid >> 5, k = (tid & 31) * 4;
    *(ushort4*)&hs[0][b * 136 + k] = (ushort4){0, 0, 0, 0};
  }
  bool vld = false;
  __syncthreads();

  ushort4 pr[4], prn[4];
  load_pr(pre2 + ((size_t)t0 * B_ + bglob) * G4_ + kq16, pr);
  load_pr(pre2 + ((size_t)(t0 + 1) * B_ + bglob) * G4_ + kq16, prn);

  ushort4 hw = {0, 0, 0, 0};
#pragma unroll 1
  for (int u = 0; u < LCH; u++) {
    const int t = t0 + u;
    ushort4 pr2[4];
    const int un = (u + 2 < LCH) ? u + 2 : LCH - 1;
    load_pr(pre2 + ((size_t)(t0 + un) * B_ + bglob) * G4_ + kq16, pr2);

    const int dn = dns[u * 16 + l15];
    vld = vld || (dn != 0);

    const unsigned short* hb = hs[u & 1];
    bf16x8 hf[4];
#pragma unroll
    for (int kc = 0; kc < 4; kc++) {
      bf16x8 v = *(const bf16x8*)&hb[l15 * 136 + kc * 32 + q * 8];
      if (dn) v = (bf16x8){0, 0, 0, 0, 0, 0, 0, 0};
      hf[kc] = v;
    }

    f32x4 acc[4];
#pragma unroll
    for (int tI = 0; tI < 4; tI++) acc[tI] = (f32x4){0.f, 0.f, 0.f, 0.f};
#pragma unroll
    for (int tI = 0; tI < 4; tI++)
#pragma unroll
      for (int kc = 0; kc < 4; kc++)
        acc[tI] = __builtin_amdgcn_mfma_f32_16x16x32_bf16(
            wf[tI][kc], hf[kc], acc[tI], 0, 0, 0);

    const float m = dn ? 0.0f : 1.0f;
    float hv[4];
#pragma unroll
    for (int r = 0; r < 4; r++) {
      const float iv = acc[0][r] + bf2f(pr[r].x);
      const float fv = acc[1][r] + bf2f(pr[r].y);
      const float gv = acc[2][r] + bf2f(pr[r].z);
      const float ov = acc[3][r] + bf2f(pr[r].w);
      float cc = c_[r] * m;
      cc = sigf(fv) * cc + sigf(iv) * tanhf_(gv);
      c_[r] = cc;
      hv[r] = sigf(ov) * tanhf_(cc);
    }
    uint2 hp = {bfpack2(hv[0], hv[1]), bfpack2(hv[2], hv[3])};
    hw = *(ushort4*)&hp;
    *(uint2*)&hs[(u + 1) & 1][l15 * 136 + kcell] = hp;
    if (vld)
      *(uint2*)&hidden[((size_t)t * B_ + bglob) * H_ + kcell] = hp;
#pragma unroll
    for (int tI = 0; tI < 4; tI++) { pr[tI] = prn[tI]; prn[tI] = pr2[tI]; }
    barrier_lds();
  }

  *(ushort4*)&hfin[((size_t)ck * B_ + bglob) * H_ + kcell] = hw;
  float4 cv = {c_[0], c_[1], c_[2], c_[3]};
  *(float4*)&cfin[((size_t)ck * B_ + bglob) * H_ + kcell] = cv;
}

__global__ __launch_bounds__(512) void k2b_par(
    const unsigned short* __restrict__ pre2, const float* __restrict__ Whh,
    const float* __restrict__ h0, const float* __restrict__ c0,
    const int* __restrict__ done, unsigned short* __restrict__ hidden,
    const unsigned short* __restrict__ hfin, const float* __restrict__ cfin,
    int* __restrict__ needfix) {
  __shared__ unsigned short hs[2][16 * 136];
  __shared__ int dns[LCH * 16];

  const int bg = blockIdx.x & 15;
  const int ck = blockIdx.x >> 4;
  const int t0 = ck * LCH;
  const int tid = threadIdx.x;
  const int w = tid >> 6;
  const int lane = tid & 63;
  const int l15 = lane & 15;
  const int q = lane >> 4;
  const int bglob = bg * 16 + l15;
  const int kcell = 16 * w + 4 * q;
  const int kq16 = kcell * 4;

  {
    const int r = tid >> 4, c = tid & 15;
    dns[tid] = done[(size_t)(t0 + r) * B_ + bg * 16 + c];
  }

  bf16x8 wf[4][4];
#pragma unroll
  for (int tI = 0; tI < 4; tI++) {
    const int jg = 16 * (w + 8 * tI) + l15;
#pragma unroll
    for (int kc = 0; kc < 4; kc++) {
      const float* p = Whh + (size_t)jg * H_ + kc * 32 + q * 8;
      float4 u0 = *(const float4*)p;
      float4 u1 = *(const float4*)(p + 4);
      bf16x8 r;
      r[0]=(short)f2bf(u0.x); r[1]=(short)f2bf(u0.y); r[2]=(short)f2bf(u0.z); r[3]=(short)f2bf(u0.w);
      r[4]=(short)f2bf(u1.x); r[5]=(short)f2bf(u1.y); r[6]=(short)f2bf(u1.z); r[7]=(short)f2bf(u1.w);
      wf[tI][kc] = r;
    }
  }

  float c_[4];
  {
    const int b = tid >> 5, k = (tid & 31) * 4;
    if (ck == 0) {
      float4 hv = *(const float4*)(h0 + (size_t)(bg * 16 + b) * H_ + k);
      uint2 hp = {bfpack2(hv.x, hv.y), bfpack2(hv.z, hv.w)};
      *(uint2*)&hs[0][b * 136 + k] = hp;
      float4 cv = *(const float4*)(c0 + (size_t)bglob * H_ + kcell);
      c_[0] = cv.x; c_[1] = cv.y; c_[2] = cv.z; c_[3] = cv.w;
    } else {
      ushort4 hv = *(const ushort4*)&hfin[((size_t)(ck - 1) * B_ + bg * 16 + b) * H_ + k];
      *(ushort4*)&hs[0][b * 136 + k] = hv;
      float4 cv = *(const float4*)&cfin[((size_t)(ck - 1) * B_ + bglob) * H_ + kcell];
      c_[0] = cv.x; c_[1] = cv.y; c_[2] = cv.z; c_[3] = cv.w;
    }
  }
  int cur = 0;
  bool act = true;
  __syncthreads();

  ushort4 pr[4], prn[4];
  load_pr(pre2 + ((size_t)t0 * B_ + bglob) * G4_ + kq16, pr);
  load_pr(pre2 + ((size_t)(t0 + 1) * B_ + bglob) * G4_ + kq16, prn);

#pragma unroll 1
  for (int u = 0; u < LCH; u++) {
    const int t = t0 + u;
    const int dn = dns[u * 16 + l15];
    const bool nact = act && (dn == 0);
    if (__ballot(nact) == 0ULL) { act = false; break; }
    act = nact;

    ushort4 pr2[4];
    const int un = (u + 2 < LCH) ? u + 2 : LCH - 1;
    load_pr(pre2 + ((size_t)(t0 + un) * B_ + bglob) * G4_ + kq16, pr2);

    const unsigned short* hb = hs[cur];
    bf16x8 hf[4];
#pragma unroll
    for (int kc = 0; kc < 4; kc++)
      hf[kc] = *(const bf16x8*)&hb[l15 * 136 + kc * 32 + q * 8];

    f32x4 acc[4];
#pragma unroll
    for (int tI = 0; tI < 4; tI++) acc[tI] = (f32x4){0.f, 0.f, 0.f, 0.f};
#pragma unroll
    for (int tI = 0; tI < 4; tI++)
#pragma unroll
      for (int kc = 0; kc < 4; kc++)
        acc[tI] = __builtin_amdgcn_mfma_f32_16x16x32_bf16(
            wf[tI][kc], hf[kc], acc[tI], 0, 0, 0);

    float hv[4];
#pragma unroll
    for (int r = 0; r < 4; r++) {
      const float iv = acc[0][r] + bf2f(pr[r].x);
      const float fv = acc[1][r] + bf2f(pr[r].y);
      const float gv = acc[2][r] + bf2f(pr[r].z);
      const float ov = acc[3][r] + bf2f(pr[r].w);
      float cc = sigf(fv) * c_[r] + sigf(iv) * tanhf_(gv);
      c_[r] = cc;
      hv[r] = sigf(ov) * tanhf_(cc);
    }
    uint2 hp = {bfpack2(hv[0], hv[1]), bfpack2(hv[2], hv[3])};
    *(uint2*)&hs[cur ^ 1][l15 * 136 + kcell] = hp;
    if (act)
      *(uint2*)&hidden[((size_t)t * B_ + bglob) * H_ + kcell] = hp;
#pragma unroll
    for (int tI = 0; tI < 4; tI++) { pr[tI] = prn[tI]; prn[tI] = pr2[tI]; }
    barrier_lds();
    cur ^= 1;
  }

  if (tid == 0) needfix[blockIdx.x] = (__ballot(act) != 0ULL) ? 1 : 0;
}

// Sequential guard: exact fallback, expected to exit immediately.
__global__ __launch_bounds__(512) void k2c_guard(
    const unsigned short* __restrict__ pre2, const float* __restrict__ Whh,
    const float* __restrict__ h0, const float* __restrict__ c0,
    const int* __restrict__ done, unsigned short* __restrict__ hidden,
    const unsigned short* __restrict__ hfin, const float* __restrict__ cfin,
    const int* __restrict__ needfix) {
  const int bg = blockIdx.x;
  bool dirty = false;
  for (int c2 = 0; c2 < NCH - 1; c2++) dirty |= (needfix[c2 * 16 + bg] != 0);
  if (!dirty) return;

  __shared__ unsigned short hs[2][16 * 136];
  __shared__ int dns[T_ * 16];

  const int tid = threadIdx.x;
  const int w = tid >> 6;
  const int lane = tid & 63;
  const int l15 = lane & 15;
  const int q = lane >> 4;
  const int bglob = bg * 16 + l15;
  const int kcell = 16 * w + 4 * q;
  const int kq16 = kcell * 4;

  {
    const int* p = done + (size_t)tid * B_ + bg * 16;
    *(int4*)&dns[tid * 16]      = *(const int4*)(p);
    *(int4*)&dns[tid * 16 + 4]  = *(const int4*)(p + 4);
    *(int4*)&dns[tid * 16 + 8]  = *(const int4*)(p + 8);
    *(int4*)&dns[tid * 16 + 12] = *(const int4*)(p + 12);
  }

  bf16x8 wf[4][4];
#pragma unroll
  for (int tI = 0; tI < 4; tI++) {
    const int jg = 16 * (w + 8 * tI) + l15;
#pragma unroll
    for (int kc = 0; kc < 4; kc++) {
      const float* p = Whh + (size_t)jg * H_ + kc * 32 + q * 8;
      float4 u0 = *(const float4*)p;
      float4 u1 = *(const float4*)(p + 4);
      bf16x8 r;
      r[0]=(short)f2bf(u0.x); r[1]=(short)f2bf(u0.y); r[2]=(short)f2bf(u0.z); r[3]=(short)f2bf(u0.w);
      r[4]=(short)f2bf(u1.x); r[5]=(short)f2bf(u1.y); r[6]=(short)f2bf(u1.z); r[7]=(short)f2bf(u1.w);
      wf[tI][kc] = r;
    }
  }

  float c_[4];
  {
    float4 cv = *(const float4*)(c0 + (size_t)bglob * H_ + kcell);
    c_[0] = cv.x; c_[1] = cv.y; c_[2] = cv.z; c_[3] = cv.w;
    const int b = tid >> 5, k = (tid & 31) * 4;
    float4 hv = *(const float4*)(h0 + (size_t)(bg * 16 + b) * H_ + k);
    uint2 hp = {bfpack2(hv.x, hv.y), bfpack2(hv.z, hv.w)};
    *(uint2*)&hs[0][b * 136 + k] = hp;
  }
  int cur = 0;
  __syncthreads();

#pragma unroll 1
  for (int ck = 0; ck < NCH; ck++) {
    const int t0 = ck * LCH;
    bool act = true;

    ushort4 pr[4];
    load_pr(pre2 + ((size_t)t0 * B_ + bglob) * G4_ + kq16, pr);

#pragma unroll 1
    for (int u = 0; u < LCH; u++) {
      const int t = t0 + u;
      const int dn = dns[t * 16 + l15];
      const bool nact = act && (dn == 0);
      if (__ballot(nact) == 0ULL) { act = false; break; }
      act = nact;

      ushort4 prn[4];
      const int un = (u + 1 < LCH) ? u + 1 : LCH - 1;
      load_pr(pre2 + ((size_t)(t0 + un) * B_ + bglob) * G4_ + kq16, prn);

      const unsigned short* hb = hs[cur];
      bf16x8 hf[4];
#pragma unroll
      for (int kc = 0; kc < 4; kc++)
        hf[kc] = *(const bf16x8*)&hb[l15 * 136 + kc * 32 + q * 8];

      f32x4 acc[4];
#pragma unroll
      for (int tI = 0; tI < 4; tI++) acc[tI] = (f32x4){0.f, 0.f, 0.f, 0.f};
#pragma unroll
      for (int tI = 0; tI < 4; tI++)
#pragma unroll
        for (int kc = 0; kc < 4; kc++)
          acc[tI] = __builtin_amdgcn_mfma_f32_16x16x32_bf16(
              wf[tI][kc], hf[kc], acc[tI], 0, 0, 0);

      float hv[4];
#pragma unroll
      for (int r = 0; r < 4; r++) {
        const float iv = acc[0][r] + bf2f(pr[r].x);
        const float fv = acc[1][r] + bf2f(pr[r].y);
        const float gv = acc[2][r] + bf2f(pr[r].z);
        const float ov = acc[3][r] + bf2f(pr[r].w);
        float cc = sigf(fv) * c_[r] + sigf(iv) * tanhf_(gv);
        c_[r] = cc;
        hv[r] = sigf(ov) * tanhf_(cc);
      }
      uint2 hp = {bfpack2(hv[0], hv[1]), bfpack2(hv[2], hv[3])};
      *(uint2*)&hs[cur ^ 1][l15 * 136 + kcell] = hp;
      if (act)
        *(uint2*)&hidden[((size_t)t * B_ + bglob) * H_ + kcell] = hp;
#pragma unroll
      for (int tI = 0; tI < 4; tI++) pr[tI] = prn[tI];
      barrier_lds();
      cur ^= 1;
    }

    if (!act) {
      ushort4 hv = *(const ushort4*)&hfin[((size_t)ck * B_ + bglob) * H_ + kcell];
      float4 cv = *(const float4*)&cfin[((size_t)ck * B_ + bglob) * H_ + kcell];
      c_[0] = cv.x; c_[1] = cv.y; c_[2] = cv.z; c_[3] = cv.w;
      *(ushort4*)&hs[cur][l15 * 136 + kcell] = hv;
    }
    barrier_lds();
  }
}

// ---------------------------------------------------------------------------
// K3: out[T*B][13] = hidden @ [W_pi; W_v]^T + [b_pi; b_v]   (unchanged)
// ---------------------------------------------------------------------------
__global__ __launch_bounds__(256) void k3_head(
    const unsigned short* __restrict__ hidden, const float* __restrict__ Wpi,
    const float* __restrict__ bpi, const float* __restrict__ Wv,
    const float* __restrict__ bv, float* __restrict__ out) {
  __shared__ unsigned short hs3[64 * 136];
  __shared__ float bias_s[16];

  const int tid = threadIdx.x;
  const int w = tid >> 6;
  const int lane = tid & 63;
  const int l15 = lane & 15;
  const int q = lane >> 4;
  const int m0 = blockIdx.x * 64;

  if (tid < 16) bias_s[tid] = (tid < 12) ? bpi[tid] : ((tid == 12) ? bv[0] : 0.f);

  bf16x8 wf3[4];
#pragma unroll
  for (int kc = 0; kc < 4; kc++) {
    float4 u0 = {0.f, 0.f, 0.f, 0.f}, u1 = {0.f, 0.f, 0.f, 0.f};
    if (l15 < 12) {
      const float* p = Wpi + (size_t)l15 * H_ + kc * 32 + q * 8;
      u0 = *(const float4*)p; u1 = *(const float4*)(p + 4);
    } else if (l15 == 12) {
      const float* p = Wv + kc * 32 + q * 8;
      u0 = *(const float4*)p; u1 = *(const float4*)(p + 4);
    }
    bf16x8 r;
    r[0]=(short)f2bf(u0.x); r[1]=(short)f2bf(u0.y); r[2]=(short)f2bf(u0.z); r[3]=(short)f2bf(u0.w);
    r[4]=(short)f2bf(u1.x); r[5]=(short)f2bf(u1.y); r[6]=(short)f2bf(u1.z); r[7]=(short)f2bf(u1.w);
    wf3[kc] = r;
  }

  {
    const int row = tid >> 2, ks = (tid & 3) * 32;
    const unsigned short* p = hidden + (size_t)(m0 + row) * H_ + ks;
#pragma unroll
    for (int i = 0; i < 4; i++)
      *(uint4*)&hs3[row * 136 + ks + i * 8] = *(const uint4*)(p + i * 8);
  }
  __syncthreads();

  f32x4 acc = (f32x4){0.f, 0.f, 0.f, 0.f};
#pragma unroll
  for (int kc = 0; kc < 4; kc++) {
    bf16x8 hf = *(bf16x8*)&hs3[(16 * w + l15) * 136 + kc * 32 + q * 8];
    acc = __builtin_amdgcn_mfma_f32_16x16x32_bf16(wf3[kc], hf, acc, 0, 0, 0);
  }

  const float4 bb = *(float4*)&bias_s[4 * q];
  const int m = m0 + 16 * w + l15;
  const size_t ro = (size_t)m * 13;
  float v0 = acc[0] + bb.x, v1 = acc[1] + bb.y, v2 = acc[2] + bb.z, v3 = acc[3] + bb.w;
  if (q < 3) {
    out[ro + 4 * q + 0] = v0;
    out[ro + 4 * q + 1] = v1;
    out[ro + 4 * q + 2] = v2;
    out[ro + 4 * q + 3] = v3;
  } else {
    out[ro + 12] = v0;
  }
}

// ---------------------------------------------------------------------------
// Workspace (ws, 167.8 MB):
//   pre2   bf16 [131072][512] @ 0            (cell-major-quad layout)
//   hidden bf16 [131072][128] @ 134,217,728
// Scratch in d_out (6.5 MB, overwritten by K3 at the end):
//   Wf bf16 frag-major [320 KB] @ 0   bias2 fp32 [512] @ 512 KB
//   hfin @ 1 MB, cfin @ 2 MB, needfix @ 4 MB
// ---------------------------------------------------------------------------
extern "C" void kernel_launch(void* const* d_in, const int* in_sizes, int n_in,
                              void* d_out, int out_size, void* d_ws, size_t ws_size,
                              hipStream_t stream) {
  const float* x    = (const float*)d_in[0];
  const int* done   = (const int*)d_in[1];
  const float* h0   = (const float*)d_in[2];
  const float* c0   = (const float*)d_in[3];
  const float* Wih  = (const float*)d_in[4];
  const float* Whh  = (const float*)d_in[5];
  const float* bih  = (const float*)d_in[6];
  const float* bhh  = (const float*)d_in[7];
  const float* Wpi  = (const float*)d_in[8];
  const float* bpi  = (const float*)d_in[9];
  const float* Wv   = (const float*)d_in[10];
  const float* bv   = (const float*)d_in[11];
  (void)in_sizes; (void)n_in; (void)out_size; (void)ws_size;

  unsigned short* pre2 = (unsigned short*)d_ws;
  unsigned short* hidden = pre2 + (size_t)TB_ * G4_;
  unsigned short* Wf   = (unsigned short*)d_out;
  float* bias2         = (float*)((char*)d_out + (512u << 10));
  unsigned short* hfin = (unsigned short*)((char*)d_out + (1u << 20));
  float* cfin          = (float*)((char*)d_out + (2u << 20));
  int* needfix         = (int*)((char*)d_out + (4u << 20));
  float* out = (float*)d_out;

  k0w_cvt<<<80, 256, 0, stream>>>(Wih, bih, bhh, Wf, bias2);
  k1_pregemm<<<256, 512, 0, stream>>>(x, Wf, bias2, pre2);
  k2a_chunk<<<256, 512, 0, stream>>>(pre2, Whh, done, hidden, hfin, cfin);
  k2b_par<<<256, 512, 0, stream>>>(pre2, Whh, h0, c0, done, hidden, hfin, cfin, needfix);
  k2c_guard<<<16, 512, 0, stream>>>(pre2, Whh, h0, c0, done, hidden, hfin, cfin, needfix);
  k3_head<<<TB_ / 64, 256, 0, stream>>>(hidden, Wpi, bpi, Wv, bv, out);
}